// Round 8
// baseline (11.175 us; speedup 1.0000x reference)
//
#include <hip/hip_runtime.h>

// Triplane aggregation, fused single kernel, 16x16x16 tiles.
//   C=32, R=128.
//   p_yz[y][z] = sum_c yz_feat[c][y][z] * W[c]
//   p_xz[x][z] = sum_c xz_feat[c][x][z] * W[C+c]
//   p_xy[x][y] = sum_c xy_feat[c][x][y] * W[2C+c]
//   out[x][y][z] = sigmoid(p_yz[y][z] + p_xz[x][z] + p_xy[x][y] + b)
// out flat index = x*16384 + y*128 + z (float32).
//
// Single barrier: weights are loaded per-lane into registers (8 x f32x4
// global loads, L1-broadcast) instead of being staged through LDS, so the
// kernel's only __syncthreads() is between projection-produce and
// broadcast-consume. Redundant projection reads (~48 MB, L2-resident) were
// shown NOT to be exposed (R4 tile change + R7 XCD pinning both null), so
// this round only trims barrier/latency overhead.

#define C 32
#define R 128
#define PLANE (R * R)   // 16384

#define BT 16           // tile edge (x, y, z all 16)

typedef float f32x4 __attribute__((ext_vector_type(4)));

__global__ __launch_bounds__(256) void triplane_fused_kernel(
        const float* __restrict__ yz,
        const float* __restrict__ xz,
        const float* __restrict__ xy,
        const float* __restrict__ W,
        const float* __restrict__ bptr,
        float* __restrict__ out) {
    __shared__ float pyz[BT][BT];
    __shared__ float pxz[BT][BT];
    __shared__ float pxy[BT][BT];

    const int bid = blockIdx.x;           // 0..511
    const int xt = bid & 7;               // XCD id under round-robin dispatch
    const int inner = bid >> 3;           // 0..63
    const int zt = inner & 7;
    const int yt = inner >> 3;
    const int x0 = xt * BT, y0 = yt * BT, z0 = zt * BT;
    const int t = threadIdx.x;            // 0..255

    // Projection phase: wave 0 -> pyz, wave 1 -> pxz, wave 2 -> pxy,
    // wave 3 waits at the barrier. Each lane computes one float4 output
    // accumulated over C; weights live in registers (no LDS, no barrier).
    const int pl = t >> 6;    // plane / wave
    const int g  = t & 63;
    if (pl < 3) {
        const int r0 = g >> 2;     // row 0..15
        const int q4 = g & 3;      // float4 column 0..3
        const float* src;
        if (pl == 0)      src = yz + (y0 + r0) * R + z0 + q4 * 4;
        else if (pl == 1) src = xz + (x0 + r0) * R + z0 + q4 * 4;
        else              src = xy + (x0 + r0) * R + y0 + q4 * 4;

        // weights for this plane -> 8 x f32x4 registers
        const f32x4* wv = reinterpret_cast<const f32x4*>(W + pl * C);
        f32x4 wr[8];
#pragma unroll
        for (int k = 0; k < 8; ++k) wr[k] = wv[k];

        f32x4 acc = {0.0f, 0.0f, 0.0f, 0.0f};
#pragma unroll
        for (int c = 0; c < C; ++c) {
            f32x4 v = *reinterpret_cast<const f32x4*>(src + c * PLANE);
            float wc = wr[c >> 2][c & 3];
            acc.x += v.x * wc; acc.y += v.y * wc;
            acc.z += v.z * wc; acc.w += v.w * wc;
        }
        float* dst = (pl == 0) ? &pyz[r0][q4 * 4]
                   : (pl == 1) ? &pxz[r0][q4 * 4]
                               : &pxy[r0][q4 * 4];
        *reinterpret_cast<f32x4*>(dst) = acc;
    }
    const float bb = bptr[0];
    __syncthreads();

    // Output: 16x16 rows x 16 z = 1024 float4, 4 per thread.
    const int z4 = t & 3;
    const int yi = (t >> 2) & 15;
    const int xi0 = t >> 6;               // 0..3
    f32x4 a = *reinterpret_cast<const f32x4*>(&pyz[yi][z4 * 4]);
#pragma unroll
    for (int it = 0; it < 4; ++it) {
        int xi = xi0 + 4 * it;            // 0..15
        float base = pxy[xi][yi] + bb;
        f32x4 c4 = *reinterpret_cast<const f32x4*>(&pxz[xi][z4 * 4]);
        f32x4 o;
        o.x = __builtin_amdgcn_rcpf(1.0f + __expf(-(a.x + c4.x + base)));
        o.y = __builtin_amdgcn_rcpf(1.0f + __expf(-(a.y + c4.y + base)));
        o.z = __builtin_amdgcn_rcpf(1.0f + __expf(-(a.z + c4.z + base)));
        o.w = __builtin_amdgcn_rcpf(1.0f + __expf(-(a.w + c4.w + base)));
        __builtin_nontemporal_store(o,
            reinterpret_cast<f32x4*>(out + (x0 + xi) * PLANE + (y0 + yi) * R + z0 + z4 * 4));
    }
}

extern "C" void kernel_launch(void* const* d_in, const int* in_sizes, int n_in,
                              void* d_out, int out_size, void* d_ws, size_t ws_size,
                              hipStream_t stream) {
    const float* yz = (const float*)d_in[0];
    const float* xz = (const float*)d_in[1];
    const float* xy = (const float*)d_in[2];
    const float* W  = (const float*)d_in[3];
    const float* b  = (const float*)d_in[4];
    float* out = (float*)d_out;

    triplane_fused_kernel<<<512, 256, 0, stream>>>(yz, xz, xy, W, b, out);
}

// Round 9
// 10.649 us; speedup vs baseline: 1.0494x; 1.0494x over previous
//
#include <hip/hip_runtime.h>
#include <hip/hip_bf16.h>

// Triplane aggregation, fused single kernel, 16x16x16 tiles, XCD-aware.
//   C=32, R=128.
//   p_yz[y][z] = sum_c yz_feat[c][y][z] * W[c]
//   p_xz[x][z] = sum_c xz_feat[c][x][z] * W[C+c]
//   p_xy[x][y] = sum_c xy_feat[c][x][y] * W[2C+c]
//   out[x][y][z] = sigmoid(p_yz[y][z] + p_xz[x][z] + p_xy[x][y] + b)
// out flat index = x*16384 + y*128 + z (float32).
//
// Best-measured configuration (10.39 us): weights staged via LDS (one cheap
// barrier; per-lane register weight loads measured +0.8 us WORSE in R8),
// XCD-pinned x-slabs, float4 projection loads, nontemporal output stores,
// rcp-based sigmoid. Remaining dur_us is dominated by a fixed replay floor:
// compulsory traffic is ~14.4 MB (~2.3 us at achievable BW) and all
// counter-visible levers (redundant reads, barriers, launch count) have
// been individually nulled.

#define C 32
#define R 128
#define PLANE (R * R)   // 16384

#define BT 16           // tile edge (x, y, z all 16)

typedef float f32x4 __attribute__((ext_vector_type(4)));

__global__ __launch_bounds__(256) void triplane_fused_kernel(
        const float* __restrict__ yz,
        const float* __restrict__ xz,
        const float* __restrict__ xy,
        const float* __restrict__ W,
        const float* __restrict__ bptr,
        float* __restrict__ out) {
    __shared__ float pyz[BT][BT];
    __shared__ float pxz[BT][BT];
    __shared__ float pxy[BT][BT];
    __shared__ float w[3 * C];

    const int bid = blockIdx.x;           // 0..511
    const int xt = bid & 7;               // XCD id under round-robin dispatch
    const int inner = bid >> 3;           // 0..63
    const int zt = inner & 7;             // fastest within XCD
    const int yt = inner >> 3;
    const int x0 = xt * BT, y0 = yt * BT, z0 = zt * BT;
    const int t = threadIdx.x;            // 0..255

    if (t < 3 * C) w[t] = W[t];
    __syncthreads();

    // Projection phase: wave 0 -> pyz, wave 1 -> pxz, wave 2 -> pxy,
    // wave 3 idle. Each lane computes one float4 (4 consecutive inner
    // coords) accumulated over C -> 32 float4 loads per lane.
    const int pl = t >> 6;    // plane / wave
    const int g  = t & 63;    // group within plane
    if (pl < 3) {
        const int r0 = g >> 2;     // row 0..15
        const int q4 = g & 3;      // float4 column 0..3
        const float* src;
        const float* wp = w + pl * C;
        if (pl == 0)      src = yz + (y0 + r0) * R + z0 + q4 * 4;
        else if (pl == 1) src = xz + (x0 + r0) * R + z0 + q4 * 4;
        else              src = xy + (x0 + r0) * R + y0 + q4 * 4;
        f32x4 acc = {0.0f, 0.0f, 0.0f, 0.0f};
#pragma unroll
        for (int c = 0; c < C; ++c) {
            f32x4 v = *reinterpret_cast<const f32x4*>(src + c * PLANE);
            float wc = wp[c];
            acc.x += v.x * wc; acc.y += v.y * wc;
            acc.z += v.z * wc; acc.w += v.w * wc;
        }
        float* dst = (pl == 0) ? &pyz[r0][q4 * 4]
                   : (pl == 1) ? &pxz[r0][q4 * 4]
                               : &pxy[r0][q4 * 4];
        *reinterpret_cast<f32x4*>(dst) = acc;
    }
    const float bb = bptr[0];
    __syncthreads();

    // Output: 16x16 rows x 16 z = 1024 float4, 4 per thread.
    const int z4 = t & 3;
    const int yi = (t >> 2) & 15;
    const int xi0 = t >> 6;               // 0..3
#pragma unroll
    for (int it = 0; it < 4; ++it) {
        int xi = xi0 + 4 * it;            // 0..15
        float base = pxy[xi][yi] + bb;
        f32x4 a = *reinterpret_cast<const f32x4*>(&pyz[yi][z4 * 4]);
        f32x4 c4 = *reinterpret_cast<const f32x4*>(&pxz[xi][z4 * 4]);
        f32x4 o;
        o.x = __builtin_amdgcn_rcpf(1.0f + __expf(-(a.x + c4.x + base)));
        o.y = __builtin_amdgcn_rcpf(1.0f + __expf(-(a.y + c4.y + base)));
        o.z = __builtin_amdgcn_rcpf(1.0f + __expf(-(a.z + c4.z + base)));
        o.w = __builtin_amdgcn_rcpf(1.0f + __expf(-(a.w + c4.w + base)));
        __builtin_nontemporal_store(o,
            reinterpret_cast<f32x4*>(out + (x0 + xi) * PLANE + (y0 + yi) * R + z0 + z4 * 4));
    }
}

extern "C" void kernel_launch(void* const* d_in, const int* in_sizes, int n_in,
                              void* d_out, int out_size, void* d_ws, size_t ws_size,
                              hipStream_t stream) {
    const float* yz = (const float*)d_in[0];
    const float* xz = (const float*)d_in[1];
    const float* xy = (const float*)d_in[2];
    const float* W  = (const float*)d_in[3];
    const float* b  = (const float*)d_in[4];
    float* out = (float*)d_out;

    triplane_fused_kernel<<<512, 256, 0, stream>>>(yz, xz, xy, W, b, out);
}